// Round 2
// baseline (18991.312 us; speedup 1.0000x reference)
//
#include <hip/hip_runtime.h>
#include <math.h>

#define B_  256
#define T_  512
#define D_  256
#define H_  1024
#define O_  128
#define N4H 4096          // 4*H

typedef __attribute__((ext_vector_type(8))) short bf16x8;
typedef __attribute__((ext_vector_type(4))) float f32x4;

__device__ __forceinline__ unsigned short f2bf(float x) {
    union { float f; unsigned u; } v; v.f = x;
    unsigned r = v.u + 0x7fffu + ((v.u >> 16) & 1u);
    return (unsigned short)(r >> 16);
}
__device__ __forceinline__ float bf2f(unsigned short b) {
    union { float f; unsigned u; } v; v.u = ((unsigned)b) << 16;
    return v.f;
}
// cheap split: hi = truncated top-16, lo = rne(w - hi).
__device__ __forceinline__ void splitf(float w, short& hi, short& lo) {
    union { float f; unsigned u; } v; v.f = w;
    union { float f; unsigned u; } hf; hf.u = v.u & 0xffff0000u;
    hi = (short)(unsigned short)(v.u >> 16);
    lo = (short)f2bf(w - hf.f);
}

// ---------------------------------------------------------------------------
// Pack weights, gate-interleaved rows n' = 4*j + gate (0=g,1=i,2=f,3=o).
// ---------------------------------------------------------------------------
__global__ __launch_bounds__(256) void pack_weights(
    const float* __restrict__ Wgx, const float* __restrict__ bgx, const float* __restrict__ Wgh,
    const float* __restrict__ Wix, const float* __restrict__ bix, const float* __restrict__ Wih,
    const float* __restrict__ Wfx, const float* __restrict__ bfx, const float* __restrict__ Wfh,
    const float* __restrict__ Wox, const float* __restrict__ box, const float* __restrict__ Woh,
    unsigned short* __restrict__ Whhi, unsigned short* __restrict__ Whlo,
    unsigned short* __restrict__ WXhi, unsigned short* __restrict__ WXlo,
    float* __restrict__ biasP)
{
    int idx = blockIdx.x * 256 + threadIdx.x;
    const int K = H_ + D_;
    const int total = N4H * K;
    if (idx < total) {
        int np = idx / K;
        int k  = idx - np * K;
        int j = np >> 2, g = np & 3;
        const float* Wh = (g == 0) ? Wgh : (g == 1) ? Wih : (g == 2) ? Wfh : Woh;
        const float* Wx = (g == 0) ? Wgx : (g == 1) ? Wix : (g == 2) ? Wfx : Wox;
        float w = (k < H_) ? Wh[j * H_ + k] : Wx[j * D_ + (k - H_)];
        unsigned short hi = f2bf(w);
        unsigned short lo = f2bf(w - bf2f(hi));
        if (k < H_) { Whhi[np * H_ + k] = hi; Whlo[np * H_ + k] = lo; }
        else        { WXhi[np * D_ + (k - H_)] = hi; WXlo[np * D_ + (k - H_)] = lo; }
    }
    if (idx < N4H) {
        int j = idx >> 2, g = idx & 3;
        const float* bx = (g == 0) ? bgx : (g == 1) ? bix : (g == 2) ? bfx : box;
        biasP[idx] = bx[j];
    }
}

// ---------------------------------------------------------------------------
// Persistent kernel: all 512 LSTM steps in one cooperative launch.
// 256 blocks x 512 threads (8 waves), 1 block/CU.
// Block (rg, cg): rows [rg*64, +64), packed cols [cg*64, +64).
// Per chunk of Tc steps:
//   phase A: compute xz tile for Tc steps (block-local, waves split over t)
//   phase B: Tc recurrent steps; per-step barrier spans only the 64 blocks
//            sharing rg (they produce exactly the h rows this cluster reads).
// c state lives in 2 VGPRs per thread for the whole run.
// ---------------------------------------------------------------------------
__global__ __launch_bounds__(512, 2) void lstm_persistent(
    const float* __restrict__ x,
    const unsigned short* __restrict__ Whhi, const unsigned short* __restrict__ Whlo,
    const unsigned short* __restrict__ WXhi, const unsigned short* __restrict__ WXlo,
    const float* __restrict__ biasP,
    unsigned short* __restrict__ h0hi, unsigned short* __restrict__ h0lo,
    unsigned short* __restrict__ h1hi, unsigned short* __restrict__ h1lo,
    float* __restrict__ xz,
    unsigned int* __restrict__ bar,      // 4 counters, 128B apart, pre-zeroed
    int Tc)
{
    __shared__ __align__(16) float zbuf[8][64][68];   // 139 KB

    const int tid  = threadIdx.x;
    const int wave = tid >> 6;
    const int lane = tid & 63;
    const int lrow = lane & 15;
    const int quad = lane >> 4;

    // XCD swizzle: fid%8 = XCD; each XCD owns 8 consecutive cgs (W L2-resident)
    const int fid = blockIdx.x;
    const int xcd = fid & 7;
    const int s   = fid >> 3;
    const int cgi = xcd * 8 + (s & 7);  // 0..63
    const int rg  = s >> 3;             // 0..3
    const int rbase = rg * 64;
    const int cbase = cgi * 64;

    // fixed epilogue ownership -> c in registers
    const int b_loc = tid >> 3;          // 0..63
    const int oc    = (tid & 7) * 8;     // 0..56
    const int bown  = rbase + b_loc;
    const int j0    = cgi * 16 + (tid & 7) * 2;
    float c0 = 0.f, c1 = 0.f;

    unsigned int* const mybar = bar + rg * 32;
    unsigned int barTarget = 0;

    for (int t0 = 0; t0 < T_; t0 += Tc) {
        const int tc = (T_ - t0 < Tc) ? (T_ - t0) : Tc;

        // ================= phase A: xz tile (block-local) ==================
        for (int t_rel = wave; t_rel < tc; t_rel += 8) {
            const int t = t0 + t_rel;
            f32x4 acc[4][4];
            #pragma unroll
            for (int rs = 0; rs < 4; ++rs)
                #pragma unroll
                for (int cs = 0; cs < 4; ++cs)
                    acc[rs][cs] = (f32x4){0.f, 0.f, 0.f, 0.f};

            #pragma unroll 1
            for (int kc = 0; kc < D_; kc += 32) {
                bf16x8 Ahi[4], Alo[4], Bh[4], Bl[4];
                #pragma unroll
                for (int rs = 0; rs < 4; ++rs) {
                    int b = rbase + rs * 16 + lrow;
                    const float* p = x + (size_t)b * (T_ * D_) + (size_t)t * D_ + kc + quad * 8;
                    float4 v0 = *(const float4*)p;
                    float4 v1 = *(const float4*)(p + 4);
                    float vv[8] = {v0.x, v0.y, v0.z, v0.w, v1.x, v1.y, v1.z, v1.w};
                    #pragma unroll
                    for (int j = 0; j < 8; ++j) {
                        short hi, lo; splitf(vv[j], hi, lo);
                        Ahi[rs][j] = hi; Alo[rs][j] = lo;
                    }
                }
                #pragma unroll
                for (int cs = 0; cs < 4; ++cs) {
                    int off = (cbase + cs * 16 + lrow) * D_ + kc + quad * 8;
                    Bh[cs] = *(const bf16x8*)(WXhi + off);
                    Bl[cs] = *(const bf16x8*)(WXlo + off);
                }
                #pragma unroll
                for (int rs = 0; rs < 4; ++rs)
                    #pragma unroll
                    for (int cs = 0; cs < 4; ++cs) {
                        acc[rs][cs] = __builtin_amdgcn_mfma_f32_16x16x32_bf16(Ahi[rs], Bh[cs], acc[rs][cs], 0, 0, 0);
                        acc[rs][cs] = __builtin_amdgcn_mfma_f32_16x16x32_bf16(Ahi[rs], Bl[cs], acc[rs][cs], 0, 0, 0);
                        acc[rs][cs] = __builtin_amdgcn_mfma_f32_16x16x32_bf16(Alo[rs], Bh[cs], acc[rs][cs], 0, 0, 0);
                    }
            }
            // write xz + bias (C/D layout: col=lane&15, row=quad*4+reg)
            #pragma unroll
            for (int cs = 0; cs < 4; ++cs) {
                int col = cbase + cs * 16 + lrow;
                float bv = biasP[col];
                #pragma unroll
                for (int rs = 0; rs < 4; ++rs) {
                    int row0 = rbase + rs * 16 + quad * 4;
                    #pragma unroll
                    for (int r = 0; r < 4; ++r)
                        xz[(size_t)(t_rel * B_ + row0 + r) * N4H + col] = acc[rs][cs][r] + bv;
                }
            }
        }
        // xz is consumed only by this block; the in-step __syncthreads()
        // (vmcnt(0)-draining) publishes it block-wide. No grid barrier needed.

        // ================= phase B: recurrent steps ========================
        for (int t_rel = 0; t_rel < tc; ++t_rel) {
            const int t = t0 + t_rel;
            const unsigned short* ih = (t & 1) ? h1hi : h0hi;
            const unsigned short* il = (t & 1) ? h1lo : h0lo;
            unsigned short* oh = (t & 1) ? h0hi : h1hi;
            unsigned short* ol = (t & 1) ? h0lo : h1lo;

            f32x4 acc[4][4];
            #pragma unroll
            for (int rs = 0; rs < 4; ++rs)
                #pragma unroll
                for (int cs = 0; cs < 4; ++cs)
                    acc[rs][cs] = (f32x4){0.f, 0.f, 0.f, 0.f};

            const int kb = wave * 128;
            #pragma unroll 2
            for (int kc = 0; kc < 128; kc += 32) {
                const int k = kb + kc + quad * 8;
                bf16x8 Ahi[4], Alo[4], Bh[4], Bl[4];
                #pragma unroll
                for (int rs = 0; rs < 4; ++rs) {
                    int off = (rbase + rs * 16 + lrow) * H_ + k;
                    Ahi[rs] = *(const bf16x8*)(ih + off);
                    Alo[rs] = *(const bf16x8*)(il + off);
                }
                #pragma unroll
                for (int cs = 0; cs < 4; ++cs) {
                    int off = (cbase + cs * 16 + lrow) * H_ + k;
                    Bh[cs] = *(const bf16x8*)(Whhi + off);
                    Bl[cs] = *(const bf16x8*)(Whlo + off);
                }
                #pragma unroll
                for (int rs = 0; rs < 4; ++rs)
                    #pragma unroll
                    for (int cs = 0; cs < 4; ++cs) {
                        acc[rs][cs] = __builtin_amdgcn_mfma_f32_16x16x32_bf16(Ahi[rs], Bh[cs], acc[rs][cs], 0, 0, 0);
                        acc[rs][cs] = __builtin_amdgcn_mfma_f32_16x16x32_bf16(Ahi[rs], Bl[cs], acc[rs][cs], 0, 0, 0);
                        acc[rs][cs] = __builtin_amdgcn_mfma_f32_16x16x32_bf16(Alo[rs], Bh[cs], acc[rs][cs], 0, 0, 0);
                    }
            }

            // per-wave partials to LDS
            #pragma unroll
            for (int rs = 0; rs < 4; ++rs)
                #pragma unroll
                for (int cs = 0; cs < 4; ++cs)
                    #pragma unroll
                    for (int r = 0; r < 4; ++r)
                        zbuf[wave][rs * 16 + quad * 4 + r][cs * 16 + lrow] = acc[rs][cs][r];
            __syncthreads();

            // reduce 8 partials + cell update (2 cells/thread)
            float zz[8];
            #pragma unroll
            for (int i = 0; i < 8; i += 4) {
                float s0 = 0.f, s1 = 0.f, s2 = 0.f, s3 = 0.f;
                #pragma unroll
                for (int w = 0; w < 8; ++w) {
                    float4 v = *(const float4*)&zbuf[w][b_loc][oc + i];
                    s0 += v.x; s1 += v.y; s2 += v.z; s3 += v.w;
                }
                zz[i] = s0; zz[i + 1] = s1; zz[i + 2] = s2; zz[i + 3] = s3;
            }

            const size_t xzoff = ((size_t)t_rel * B_ + bown) * N4H + cbase + oc;
            float4 xa = *(const float4*)(xz + xzoff);
            float4 xb = *(const float4*)(xz + xzoff + 4);
            zz[0] += xa.x; zz[1] += xa.y; zz[2] += xa.z; zz[3] += xa.w;
            zz[4] += xb.x; zz[5] += xb.y; zz[6] += xb.z; zz[7] += xb.w;

            float cold[2] = {c0, c1};
            unsigned short hh[2], hl[2];
            float cnew[2];
            #pragma unroll
            for (int j = 0; j < 2; ++j) {
                float zg = zz[4 * j + 0];
                float zi = zz[4 * j + 1];
                float zf = zz[4 * j + 2];
                float zo = zz[4 * j + 3];
                float g  = tanhf(zg);
                float ig = 1.f / (1.f + expf(-zi));
                float fg = 1.f / (1.f + expf(-zf));
                float og = 1.f / (1.f + expf(-zo));
                float cn = g * ig + cold[j] * fg;
                float hn = tanhf(cn) * og;
                cnew[j] = cn;
                unsigned short h16 = f2bf(hn);
                hh[j] = h16;
                hl[j] = f2bf(hn - bf2f(h16));
            }
            c0 = cnew[0]; c1 = cnew[1];
            *(ushort2*)&oh[bown * H_ + j0] = make_ushort2(hh[0], hh[1]);
            *(ushort2*)&ol[bown * H_ + j0] = make_ushort2(hl[0], hl[1]);

            // ---- per-rg cluster barrier (64 blocks), monotone counter ----
            if (t != T_ - 1) {
                barTarget += 64;
                if (tid == 0) {
                    __threadfence();                       // release h writes
                    atomicAdd(mybar, 1u);
                    while (__hip_atomic_load(mybar, __ATOMIC_RELAXED,
                                             __HIP_MEMORY_SCOPE_AGENT) < barTarget)
                        __builtin_amdgcn_s_sleep(1);
                    __threadfence();                       // acquire peers' h
                }
            }
            __syncthreads();
        }
    }
}

// ---------------------------------------------------------------------------
// Final projection + softmax: one block per batch row, 128 threads.
// ---------------------------------------------------------------------------
__global__ __launch_bounds__(128) void final_proj(
    const unsigned short* __restrict__ hhi, const unsigned short* __restrict__ hlo,
    const float* __restrict__ Why, const float* __restrict__ bhy,
    float* __restrict__ out)
{
    __shared__ float hsh[H_];
    __shared__ float red[O_];
    const int b = blockIdx.x, tid = threadIdx.x;

    for (int k = tid; k < H_; k += O_)
        hsh[k] = bf2f(hhi[(size_t)b * H_ + k]) + bf2f(hlo[(size_t)b * H_ + k]);
    __syncthreads();

    float s = bhy[tid];
    const float* w = Why + (size_t)tid * H_;
    #pragma unroll 4
    for (int k = 0; k < H_; k += 4) {
        float4 wv = *(const float4*)(w + k);
        s += hsh[k] * wv.x + hsh[k + 1] * wv.y + hsh[k + 2] * wv.z + hsh[k + 3] * wv.w;
    }

    red[tid] = s; __syncthreads();
    for (int off = 64; off > 0; off >>= 1) {
        if (tid < off) red[tid] = fmaxf(red[tid], red[tid + off]);
        __syncthreads();
    }
    float mx = red[0]; __syncthreads();
    float e = expf(s - mx);
    red[tid] = e; __syncthreads();
    for (int off = 64; off > 0; off >>= 1) {
        if (tid < off) red[tid] += red[tid + off];
        __syncthreads();
    }
    out[(size_t)b * O_ + tid] = e / red[0];
}

// ---------------------------------------------------------------------------
extern "C" void kernel_launch(void* const* d_in, const int* in_sizes, int n_in,
                              void* d_out, int out_size, void* d_ws, size_t ws_size,
                              hipStream_t stream)
{
    const float* x   = (const float*)d_in[0];
    const float* Wgx = (const float*)d_in[1];
    const float* bgx = (const float*)d_in[2];
    const float* Wgh = (const float*)d_in[3];
    const float* Wix = (const float*)d_in[4];
    const float* bix = (const float*)d_in[5];
    const float* Wih = (const float*)d_in[6];
    const float* Wfx = (const float*)d_in[7];
    const float* bfx = (const float*)d_in[8];
    const float* Wfh = (const float*)d_in[9];
    const float* Wox = (const float*)d_in[10];
    const float* box = (const float*)d_in[11];
    const float* Woh = (const float*)d_in[12];
    const float* Why = (const float*)d_in[13];
    const float* bhy = (const float*)d_in[14];

    // workspace layout (fixed ~22 MB + xz chunk buffer)
    unsigned short* Whhi = (unsigned short*)d_ws;                 // 4096*1024
    unsigned short* Whlo = Whhi + (size_t)N4H * H_;
    unsigned short* WXhi = Whlo + (size_t)N4H * H_;               // 4096*256
    unsigned short* WXlo = WXhi + (size_t)N4H * D_;
    float*          bP   = (float*)(WXlo + (size_t)N4H * D_);
    unsigned int*   bars = (unsigned int*)(bP + N4H);             // 4 x 128B
    unsigned short* hA_hi = (unsigned short*)(bars + 128);
    unsigned short* hA_lo = hA_hi + (size_t)B_ * H_;
    unsigned short* hB_hi = hA_lo + (size_t)B_ * H_;
    unsigned short* hB_lo = hB_hi + (size_t)B_ * H_;
    float*          xz    = (float*)(hB_lo + (size_t)B_ * H_);

    const size_t fixed_bytes = (size_t)((char*)xz - (char*)d_ws);
    const size_t per_t = (size_t)B_ * N4H * sizeof(float);        // 4 MB per step
    int Tc = 1;
    if (ws_size > fixed_bytes) {
        size_t fit = (ws_size - fixed_bytes) / per_t;
        Tc = (fit > 64) ? 64 : (fit < 1 ? 1 : (int)fit);
    }

    // zero barrier counters + h ping buffer (bars, hA_hi, hA_lo contiguous)
    hipMemsetAsync(bars, 0, 512 + (size_t)B_ * H_ * 4, stream);

    const int totalW = N4H * (H_ + D_);
    pack_weights<<<(totalW + 255) / 256, 256, 0, stream>>>(
        Wgx, bgx, Wgh, Wix, bix, Wih, Wfx, bfx, Wfh, Wox, box, Woh,
        Whhi, Whlo, WXhi, WXlo, bP);

    void* kargs[] = {
        (void*)&x, (void*)&Whhi, (void*)&Whlo, (void*)&WXhi, (void*)&WXlo,
        (void*)&bP, (void*)&hA_hi, (void*)&hA_lo, (void*)&hB_hi, (void*)&hB_lo,
        (void*)&xz, (void*)&bars, (void*)&Tc
    };
    hipLaunchCooperativeKernel((const void*)lstm_persistent,
                               dim3(256), dim3(512), kargs, 0, stream);

    // T=512 even: last step (t=511, odd) wrote the A buffers
    final_proj<<<B_, 128, 0, stream>>>(hA_hi, hA_lo, Why, bhy, (float*)d_out);
}

// Round 3
// 11668.004 us; speedup vs baseline: 1.6276x; 1.6276x over previous
//
#include <hip/hip_runtime.h>
#include <math.h>

#define B_  256
#define T_  512
#define D_  256
#define H_  1024
#define O_  128
#define N4H 4096          // 4*H

typedef __attribute__((ext_vector_type(8))) short bf16x8;
typedef __attribute__((ext_vector_type(4))) float f32x4;

__device__ __forceinline__ unsigned short f2bf(float x) {
    union { float f; unsigned u; } v; v.f = x;
    unsigned r = v.u + 0x7fffu + ((v.u >> 16) & 1u);
    return (unsigned short)(r >> 16);
}
__device__ __forceinline__ float bf2f(unsigned short b) {
    union { float f; unsigned u; } v; v.u = ((unsigned)b) << 16;
    return v.f;
}
// cheap split: hi = truncated top-16, lo = rne(w - hi).
__device__ __forceinline__ void splitf(float w, short& hi, short& lo) {
    union { float f; unsigned u; } v; v.f = w;
    union { float f; unsigned u; } hf; hf.u = v.u & 0xffff0000u;
    hi = (short)(unsigned short)(v.u >> 16);
    lo = (short)f2bf(w - hf.f);
}

// Batched coherent loads: 8 x 16B from L3 (sc0 sc1 bypass L1/L2), one wait.
// waitcnt lives INSIDE the asm -> consumers (reg-dependent MFMAs) can't be
// hoisted past it (rule-18 safe).
__device__ __forceinline__ void load_h_batch(
    const unsigned short* a0, const unsigned short* a1,
    const unsigned short* a2, const unsigned short* a3,
    const unsigned short* b0, const unsigned short* b1,
    const unsigned short* b2, const unsigned short* b3,
    bf16x8& r0, bf16x8& r1, bf16x8& r2, bf16x8& r3,
    bf16x8& r4, bf16x8& r5, bf16x8& r6, bf16x8& r7)
{
    asm volatile(
        "global_load_dwordx4 %0, %8, off sc0 sc1\n\t"
        "global_load_dwordx4 %1, %9, off sc0 sc1\n\t"
        "global_load_dwordx4 %2, %10, off sc0 sc1\n\t"
        "global_load_dwordx4 %3, %11, off sc0 sc1\n\t"
        "global_load_dwordx4 %4, %12, off sc0 sc1\n\t"
        "global_load_dwordx4 %5, %13, off sc0 sc1\n\t"
        "global_load_dwordx4 %6, %14, off sc0 sc1\n\t"
        "global_load_dwordx4 %7, %15, off sc0 sc1\n\t"
        "s_waitcnt vmcnt(0)"
        : "=&v"(r0), "=&v"(r1), "=&v"(r2), "=&v"(r3),
          "=&v"(r4), "=&v"(r5), "=&v"(r6), "=&v"(r7)
        : "v"(a0), "v"(a1), "v"(a2), "v"(a3),
          "v"(b0), "v"(b1), "v"(b2), "v"(b3)
        : "memory");
}

// Coherent 4B store (sc0 sc1: write to coherence point, no L2 allocation).
__device__ __forceinline__ void store_h4(unsigned short* p, unsigned int d) {
    asm volatile("global_store_dword %0, %1, off sc0 sc1"
                 :: "v"(p), "v"(d) : "memory");
}

// ---------------------------------------------------------------------------
// Pack weights, gate-interleaved rows n' = 4*j + gate (0=g,1=i,2=f,3=o).
// ---------------------------------------------------------------------------
__global__ __launch_bounds__(256) void pack_weights(
    const float* __restrict__ Wgx, const float* __restrict__ bgx, const float* __restrict__ Wgh,
    const float* __restrict__ Wix, const float* __restrict__ bix, const float* __restrict__ Wih,
    const float* __restrict__ Wfx, const float* __restrict__ bfx, const float* __restrict__ Wfh,
    const float* __restrict__ Wox, const float* __restrict__ box, const float* __restrict__ Woh,
    unsigned short* __restrict__ Whhi, unsigned short* __restrict__ Whlo,
    unsigned short* __restrict__ WXhi, unsigned short* __restrict__ WXlo,
    float* __restrict__ biasP)
{
    int idx = blockIdx.x * 256 + threadIdx.x;
    const int K = H_ + D_;
    const int total = N4H * K;
    if (idx < total) {
        int np = idx / K;
        int k  = idx - np * K;
        int j = np >> 2, g = np & 3;
        const float* Wh = (g == 0) ? Wgh : (g == 1) ? Wih : (g == 2) ? Wfh : Woh;
        const float* Wx = (g == 0) ? Wgx : (g == 1) ? Wix : (g == 2) ? Wfx : Wox;
        float w = (k < H_) ? Wh[j * H_ + k] : Wx[j * D_ + (k - H_)];
        unsigned short hi = f2bf(w);
        unsigned short lo = f2bf(w - bf2f(hi));
        if (k < H_) { Whhi[np * H_ + k] = hi; Whlo[np * H_ + k] = lo; }
        else        { WXhi[np * D_ + (k - H_)] = hi; WXlo[np * D_ + (k - H_)] = lo; }
    }
    if (idx < N4H) {
        int j = idx >> 2, g = idx & 3;
        const float* bx = (g == 0) ? bgx : (g == 1) ? bix : (g == 2) ? bfx : box;
        biasP[idx] = bx[j];
    }
}

// ---------------------------------------------------------------------------
// Persistent kernel: all 512 LSTM steps in one cooperative launch.
// 256 blocks x 512 threads (8 waves), 1 block/CU (LDS-limited).
// Block (rg, cg): rows [rg*64,+64), packed cols [cg*64,+64).
// Clusters (rg) are fully independent: h rows of rg are produced and consumed
// only by the 64 blocks sharing rg -> per-rg 64-block barrier.
// NO cache-invalidating fences: h goes through L3 via sc0/sc1 accesses;
// weights stay plain -> L2-resident for the whole run.
// c state lives in 2 VGPRs per thread.
// ---------------------------------------------------------------------------
__global__ __launch_bounds__(512, 2) void lstm_persistent(
    const float* __restrict__ x,
    const unsigned short* __restrict__ Whhi, const unsigned short* __restrict__ Whlo,
    const unsigned short* __restrict__ WXhi, const unsigned short* __restrict__ WXlo,
    const float* __restrict__ biasP,
    unsigned short* __restrict__ h0hi, unsigned short* __restrict__ h0lo,
    unsigned short* __restrict__ h1hi, unsigned short* __restrict__ h1lo,
    float* __restrict__ xz,
    unsigned int* __restrict__ bar,      // 4 counters, 128B apart, pre-zeroed
    int Tc)
{
    __shared__ __align__(16) float zbuf[8][64][68];   // 139 KB

    const int tid  = threadIdx.x;
    const int wave = tid >> 6;
    const int lane = tid & 63;
    const int lrow = lane & 15;
    const int quad = lane >> 4;

    // XCD swizzle: fid%8 = XCD; each XCD owns 8 consecutive cgs (W L2-resident)
    const int fid = blockIdx.x;
    const int xcd = fid & 7;
    const int s   = fid >> 3;
    const int cgi = xcd * 8 + (s & 7);  // 0..63
    const int rg  = s >> 3;             // 0..3
    const int rbase = rg * 64;
    const int cbase = cgi * 64;

    // fixed epilogue ownership -> c in registers
    const int b_loc = tid >> 3;          // 0..63
    const int oc    = (tid & 7) * 8;     // 0..56
    const int bown  = rbase + b_loc;
    const int j0    = cgi * 16 + (tid & 7) * 2;
    float c0 = 0.f, c1 = 0.f;

    unsigned int* const mybar = bar + rg * 32;
    unsigned int barTarget = 0;

    for (int t0 = 0; t0 < T_; t0 += Tc) {
        const int tc = (T_ - t0 < Tc) ? (T_ - t0) : Tc;

        // ================= phase A: xz tile (block-local, plain mem) =======
        for (int t_rel = wave; t_rel < tc; t_rel += 8) {
            const int t = t0 + t_rel;
            f32x4 acc[4][4];
            #pragma unroll
            for (int rs = 0; rs < 4; ++rs)
                #pragma unroll
                for (int cs = 0; cs < 4; ++cs)
                    acc[rs][cs] = (f32x4){0.f, 0.f, 0.f, 0.f};

            #pragma unroll 1
            for (int kc = 0; kc < D_; kc += 32) {
                bf16x8 Ahi[4], Alo[4], Bh[4], Bl[4];
                #pragma unroll
                for (int rs = 0; rs < 4; ++rs) {
                    int b = rbase + rs * 16 + lrow;
                    const float* p = x + (size_t)b * (T_ * D_) + (size_t)t * D_ + kc + quad * 8;
                    float4 v0 = *(const float4*)p;
                    float4 v1 = *(const float4*)(p + 4);
                    float vv[8] = {v0.x, v0.y, v0.z, v0.w, v1.x, v1.y, v1.z, v1.w};
                    #pragma unroll
                    for (int j = 0; j < 8; ++j) {
                        short hi, lo; splitf(vv[j], hi, lo);
                        Ahi[rs][j] = hi; Alo[rs][j] = lo;
                    }
                }
                #pragma unroll
                for (int cs = 0; cs < 4; ++cs) {
                    int off = (cbase + cs * 16 + lrow) * D_ + kc + quad * 8;
                    Bh[cs] = *(const bf16x8*)(WXhi + off);
                    Bl[cs] = *(const bf16x8*)(WXlo + off);
                }
                #pragma unroll
                for (int rs = 0; rs < 4; ++rs)
                    #pragma unroll
                    for (int cs = 0; cs < 4; ++cs) {
                        acc[rs][cs] = __builtin_amdgcn_mfma_f32_16x16x32_bf16(Ahi[rs], Bh[cs], acc[rs][cs], 0, 0, 0);
                        acc[rs][cs] = __builtin_amdgcn_mfma_f32_16x16x32_bf16(Ahi[rs], Bl[cs], acc[rs][cs], 0, 0, 0);
                        acc[rs][cs] = __builtin_amdgcn_mfma_f32_16x16x32_bf16(Alo[rs], Bh[cs], acc[rs][cs], 0, 0, 0);
                    }
            }
            // write xz + bias (C/D layout: col=lane&15, row=quad*4+reg)
            #pragma unroll
            for (int cs = 0; cs < 4; ++cs) {
                int col = cbase + cs * 16 + lrow;
                float bv = biasP[col];
                #pragma unroll
                for (int rs = 0; rs < 4; ++rs) {
                    int row0 = rbase + rs * 16 + quad * 4;
                    #pragma unroll
                    for (int r = 0; r < 4; ++r)
                        xz[(size_t)(t_rel * B_ + row0 + r) * N4H + col] = acc[rs][cs][r] + bv;
                }
            }
        }
        // xz is block-local; the in-step __syncthreads() publishes it.

        // ================= phase B: recurrent steps ========================
        for (int t_rel = 0; t_rel < tc; ++t_rel) {
            const int t = t0 + t_rel;
            const unsigned short* ih = (t & 1) ? h1hi : h0hi;
            const unsigned short* il = (t & 1) ? h1lo : h0lo;
            unsigned short* oh = (t & 1) ? h0hi : h1hi;
            unsigned short* ol = (t & 1) ? h0lo : h1lo;

            f32x4 acc[4][4];
            #pragma unroll
            for (int rs = 0; rs < 4; ++rs)
                #pragma unroll
                for (int cs = 0; cs < 4; ++cs)
                    acc[rs][cs] = (f32x4){0.f, 0.f, 0.f, 0.f};

            const int kb = wave * 128;
            #pragma unroll 1
            for (int kc = 0; kc < 128; kc += 32) {
                const int k = kb + kc + quad * 8;
                bf16x8 Ahi[4], Alo[4], Bh[4], Bl[4];
                // weights: plain loads -> stay L2-cached across all steps
                #pragma unroll
                for (int cs = 0; cs < 4; ++cs) {
                    int off = (cbase + cs * 16 + lrow) * H_ + k;
                    Bh[cs] = *(const bf16x8*)(Whhi + off);
                    Bl[cs] = *(const bf16x8*)(Whlo + off);
                }
                // h: coherent batched loads from L3 (bypass L1/L2, no fence)
                const int r0o = (rbase + 0 * 16 + lrow) * H_ + k;
                const int r1o = (rbase + 1 * 16 + lrow) * H_ + k;
                const int r2o = (rbase + 2 * 16 + lrow) * H_ + k;
                const int r3o = (rbase + 3 * 16 + lrow) * H_ + k;
                load_h_batch(ih + r0o, ih + r1o, ih + r2o, ih + r3o,
                             il + r0o, il + r1o, il + r2o, il + r3o,
                             Ahi[0], Ahi[1], Ahi[2], Ahi[3],
                             Alo[0], Alo[1], Alo[2], Alo[3]);
                #pragma unroll
                for (int rs = 0; rs < 4; ++rs)
                    #pragma unroll
                    for (int cs = 0; cs < 4; ++cs) {
                        acc[rs][cs] = __builtin_amdgcn_mfma_f32_16x16x32_bf16(Ahi[rs], Bh[cs], acc[rs][cs], 0, 0, 0);
                        acc[rs][cs] = __builtin_amdgcn_mfma_f32_16x16x32_bf16(Ahi[rs], Bl[cs], acc[rs][cs], 0, 0, 0);
                        acc[rs][cs] = __builtin_amdgcn_mfma_f32_16x16x32_bf16(Alo[rs], Bh[cs], acc[rs][cs], 0, 0, 0);
                    }
            }

            // per-wave partials to LDS
            #pragma unroll
            for (int rs = 0; rs < 4; ++rs)
                #pragma unroll
                for (int cs = 0; cs < 4; ++cs)
                    #pragma unroll
                    for (int r = 0; r < 4; ++r)
                        zbuf[wave][rs * 16 + quad * 4 + r][cs * 16 + lrow] = acc[rs][cs][r];
            __syncthreads();

            // reduce 8 partials + cell update (2 cells/thread)
            float zz[8];
            #pragma unroll
            for (int i = 0; i < 8; i += 4) {
                float s0 = 0.f, s1 = 0.f, s2 = 0.f, s3 = 0.f;
                #pragma unroll
                for (int w = 0; w < 8; ++w) {
                    float4 v = *(const float4*)&zbuf[w][b_loc][oc + i];
                    s0 += v.x; s1 += v.y; s2 += v.z; s3 += v.w;
                }
                zz[i] = s0; zz[i + 1] = s1; zz[i + 2] = s2; zz[i + 3] = s3;
            }

            const size_t xzoff = ((size_t)t_rel * B_ + bown) * N4H + cbase + oc;
            float4 xa = *(const float4*)(xz + xzoff);
            float4 xb = *(const float4*)(xz + xzoff + 4);
            zz[0] += xa.x; zz[1] += xa.y; zz[2] += xa.z; zz[3] += xa.w;
            zz[4] += xb.x; zz[5] += xb.y; zz[6] += xb.z; zz[7] += xb.w;

            float cold[2] = {c0, c1};
            unsigned short hh[2], hl[2];
            float cnew[2];
            #pragma unroll
            for (int j = 0; j < 2; ++j) {
                float zg = zz[4 * j + 0];
                float zi = zz[4 * j + 1];
                float zf = zz[4 * j + 2];
                float zo = zz[4 * j + 3];
                float g  = tanhf(zg);
                float ig = 1.f / (1.f + expf(-zi));
                float fg = 1.f / (1.f + expf(-zf));
                float og = 1.f / (1.f + expf(-zo));
                float cn = g * ig + cold[j] * fg;
                float hn = tanhf(cn) * og;
                cnew[j] = cn;
                unsigned short h16 = f2bf(hn);
                hh[j] = h16;
                hl[j] = f2bf(hn - bf2f(h16));
            }
            c0 = cnew[0]; c1 = cnew[1];
            // coherent stores to L3 (no L2 dirty lines)
            store_h4(&oh[bown * H_ + j0], (unsigned)hh[0] | ((unsigned)hh[1] << 16));
            store_h4(&ol[bown * H_ + j0], (unsigned)hl[0] | ((unsigned)hl[1] << 16));

            // ---- per-rg cluster barrier (64 blocks), no fences ----
            // __syncthreads drains every thread's vmem (stores at L3) first.
            __syncthreads();
            if (t != T_ - 1) {
                barTarget += 64;
                if (tid == 0) {
                    __hip_atomic_fetch_add(mybar, 1u, __ATOMIC_RELAXED,
                                           __HIP_MEMORY_SCOPE_AGENT);
                    while (__hip_atomic_load(mybar, __ATOMIC_RELAXED,
                                             __HIP_MEMORY_SCOPE_AGENT) < barTarget)
                        __builtin_amdgcn_s_sleep(1);
                }
                __syncthreads();
            }
        }
    }
}

// ---------------------------------------------------------------------------
// Final projection + softmax: one block per batch row, 128 threads.
// ---------------------------------------------------------------------------
__global__ __launch_bounds__(128) void final_proj(
    const unsigned short* __restrict__ hhi, const unsigned short* __restrict__ hlo,
    const float* __restrict__ Why, const float* __restrict__ bhy,
    float* __restrict__ out)
{
    __shared__ float hsh[H_];
    __shared__ float red[O_];
    const int b = blockIdx.x, tid = threadIdx.x;

    for (int k = tid; k < H_; k += O_)
        hsh[k] = bf2f(hhi[(size_t)b * H_ + k]) + bf2f(hlo[(size_t)b * H_ + k]);
    __syncthreads();

    float s = bhy[tid];
    const float* w = Why + (size_t)tid * H_;
    #pragma unroll 4
    for (int k = 0; k < H_; k += 4) {
        float4 wv = *(const float4*)(w + k);
        s += hsh[k] * wv.x + hsh[k + 1] * wv.y + hsh[k + 2] * wv.z + hsh[k + 3] * wv.w;
    }

    red[tid] = s; __syncthreads();
    for (int off = 64; off > 0; off >>= 1) {
        if (tid < off) red[tid] = fmaxf(red[tid], red[tid + off]);
        __syncthreads();
    }
    float mx = red[0]; __syncthreads();
    float e = expf(s - mx);
    red[tid] = e; __syncthreads();
    for (int off = 64; off > 0; off >>= 1) {
        if (tid < off) red[tid] += red[tid + off];
        __syncthreads();
    }
    out[(size_t)b * O_ + tid] = e / red[0];
}

// ---------------------------------------------------------------------------
extern "C" void kernel_launch(void* const* d_in, const int* in_sizes, int n_in,
                              void* d_out, int out_size, void* d_ws, size_t ws_size,
                              hipStream_t stream)
{
    const float* x   = (const float*)d_in[0];
    const float* Wgx = (const float*)d_in[1];
    const float* bgx = (const float*)d_in[2];
    const float* Wgh = (const float*)d_in[3];
    const float* Wix = (const float*)d_in[4];
    const float* bix = (const float*)d_in[5];
    const float* Wih = (const float*)d_in[6];
    const float* Wfx = (const float*)d_in[7];
    const float* bfx = (const float*)d_in[8];
    const float* Wfh = (const float*)d_in[9];
    const float* Wox = (const float*)d_in[10];
    const float* box = (const float*)d_in[11];
    const float* Woh = (const float*)d_in[12];
    const float* Why = (const float*)d_in[13];
    const float* bhy = (const float*)d_in[14];

    // workspace layout (fixed ~22 MB + xz chunk buffer)
    unsigned short* Whhi = (unsigned short*)d_ws;                 // 4096*1024
    unsigned short* Whlo = Whhi + (size_t)N4H * H_;
    unsigned short* WXhi = Whlo + (size_t)N4H * H_;               // 4096*256
    unsigned short* WXlo = WXhi + (size_t)N4H * D_;
    float*          bP   = (float*)(WXlo + (size_t)N4H * D_);
    unsigned int*   bars = (unsigned int*)(bP + N4H);             // 4 x 128B
    unsigned short* hA_hi = (unsigned short*)(bars + 128);
    unsigned short* hA_lo = hA_hi + (size_t)B_ * H_;
    unsigned short* hB_hi = hA_lo + (size_t)B_ * H_;
    unsigned short* hB_lo = hB_hi + (size_t)B_ * H_;
    float*          xz    = (float*)(hB_lo + (size_t)B_ * H_);

    const size_t fixed_bytes = (size_t)((char*)xz - (char*)d_ws);
    const size_t per_t = (size_t)B_ * N4H * sizeof(float);        // 4 MB per step
    int Tc = 1;
    if (ws_size > fixed_bytes) {
        size_t fit = (ws_size - fixed_bytes) / per_t;
        Tc = (fit > 32) ? 32 : (fit < 1 ? 1 : (int)fit);          // cap: keep xz window L3-resident
    }

    // zero barrier counters + h ping buffer (bars, hA_hi, hA_lo contiguous)
    hipMemsetAsync(bars, 0, 512 + (size_t)B_ * H_ * 4, stream);

    const int totalW = N4H * (H_ + D_);
    pack_weights<<<(totalW + 255) / 256, 256, 0, stream>>>(
        Wgx, bgx, Wgh, Wix, bix, Wih, Wfx, bfx, Wfh, Wox, box, Woh,
        Whhi, Whlo, WXhi, WXlo, bP);

    void* kargs[] = {
        (void*)&x, (void*)&Whhi, (void*)&Whlo, (void*)&WXhi, (void*)&WXlo,
        (void*)&bP, (void*)&hA_hi, (void*)&hA_lo, (void*)&hB_hi, (void*)&hB_lo,
        (void*)&xz, (void*)&bars, (void*)&Tc
    };
    hipLaunchCooperativeKernel((const void*)lstm_persistent,
                               dim3(256), dim3(512), kargs, 0, stream);

    // T=512 even: last step (t=511, odd) wrote the A buffers
    final_proj<<<B_, 128, 0, stream>>>(hA_hi, hA_lo, Why, bhy, (float*)d_out);
}